// Round 4
// baseline (13.025 us; speedup 1.0000x reference)
//
#include <hip/hip_runtime.h>

// out[b,c,m] = max_n x[b,c,n] * Bt[m,n],  Bt binary {0,1}, ~3 ones per row of 2048.
// Exact sparse evaluation, ONE WAVE PER ROW, no LDS, no barriers, no atomics:
//   - wave loads its 8 KB row as 8 float4 per lane (independent -> full MLP)
//   - one ballot per 256-element chunk finds nonzero lanes (~69% skip)
//   - column index derived arithmetically from lane id (no data shuffles)
//   - lanes 0..31 (one per (b,c) channel) fmax-gather x at found columns
//   - wave-uniform nonzero count: cnt < 2048 -> a zero term exists -> clamp
//     at 0 (the dense x*0 terms); cnt == 2048 -> no clamp (all-ones row).
// Every output element has exactly one writer -> plain stores, 1 dispatch.

#define HG_N_IN   2048
#define HG_N_OUT  4096
#define HG_BC     32      // BATCH * FEAT = 2*16

__global__ __launch_bounds__(256) void hg_rowmax(const float4* __restrict__ Bt4,
                                                 const float* __restrict__ x,
                                                 float* __restrict__ out) {
    const int wavesPerBlk = blockDim.x >> 6;
    const int m    = blockIdx.x * wavesPerBlk + (threadIdx.x >> 6);  // row
    const int lane = threadIdx.x & 63;
    if (m >= HG_N_OUT) return;

    const float4* row = Bt4 + (size_t)m * (HG_N_IN / 4);
    float4 v[8];
    #pragma unroll
    for (int i = 0; i < 8; ++i) v[i] = row[lane + (i << 6)];  // all 8 in flight

    const float* xr = x + (size_t)(lane & (HG_BC - 1)) * HG_N_IN;
    float mx = -INFINITY;
    int cnt = 0;

    #pragma unroll
    for (int i = 0; i < 8; ++i) {
        int code = (v[i].x != 0.0f) | ((v[i].y != 0.0f) << 1) |
                   ((v[i].z != 0.0f) << 2) | ((v[i].w != 0.0f) << 3);
        unsigned long long b = __ballot(code != 0);
        if (b == 0ull) continue;                  // wave-uniform skip
        while (b) {
            int s = __ffsll((unsigned long long)b) - 1;
            b &= b - 1;
            int c = __shfl(code, s);              // 4-bit component mask of lane s
            int nbase = (s + (i << 6)) << 2;      // column of lane s's float4
            while (c) {
                int j = __ffs(c) - 1;
                c &= c - 1;
                ++cnt;                            // wave-uniform total
                if (lane < HG_BC) mx = fmaxf(mx, xr[nbase + j]);
            }
        }
    }

    if (lane < HG_BC) {
        float r = (cnt == HG_N_IN) ? mx : fmaxf(mx, 0.0f);  // clamp iff a zero exists
        out[(size_t)lane * HG_N_OUT + m] = r;
    }
}

extern "C" void kernel_launch(void* const* d_in, const int* in_sizes, int n_in,
                              void* d_out, int out_size, void* d_ws, size_t ws_size,
                              hipStream_t stream) {
    const float* x    = (const float*)d_in[0];   // [2,16,2048] f32
    const float4* Bt4 = (const float4*)d_in[1];  // [4096,2048] f32 as float4
    float* out = (float*)d_out;                  // [2,16,4096] f32

    // 4 waves per block, one row per wave -> 1024 blocks
    hg_rowmax<<<HG_N_OUT / 4, 256, 0, stream>>>(Bt4, x, out);
}

// Round 5
// 12.320 us; speedup vs baseline: 1.0573x; 1.0573x over previous
//
#include <hip/hip_runtime.h>

// out[b,c,m] = max_n x[b,c,n] * Bt[m,n],  Bt binary {0,1}, ~3 ones per row of 2048.
// Exact sparse evaluation, one wave per row, 16 rows per 1024-thread block:
//   - wave loads its 8 KB row as 8 float4 per lane (all in flight, coalesced)
//   - one ballot per 256-element chunk finds nonzero lanes (~69% skip)
//   - lanes 0..31 (one per (b,c) channel) fmax-gather x at found columns
//   - wave-uniform nonzero count: cnt < 2048 -> a zero term exists -> clamp
//     at 0 (the dense x*0 terms); cnt == 2048 -> no clamp (all-ones row).
//   - results staged in LDS r[16][33], then stored TRANSPOSED so each (b,c)
//     channel writes 16 consecutive floats (64 B full lines) -> write traffic
//     drops from ~8 MB of 4B-per-line partial RMW to the exact 512 KB.
// Every output element has exactly one writer -> plain stores, 1 dispatch.

#define HG_N_IN   2048
#define HG_N_OUT  4096
#define HG_BC     32      // BATCH * FEAT = 2*16
#define HG_RPB    16      // rows per block (= waves per block)

__global__ __launch_bounds__(1024) void hg_rowmax(const float4* __restrict__ Bt4,
                                                  const float* __restrict__ x,
                                                  float* __restrict__ out) {
    __shared__ float r[HG_RPB][HG_BC + 1];       // +1 pad: near-conflict-free transpose
    const int w    = threadIdx.x >> 6;           // wave id = row within block
    const int lane = threadIdx.x & 63;
    const int m0   = blockIdx.x * HG_RPB;
    const int m    = m0 + w;

    const float4* row = Bt4 + (size_t)m * (HG_N_IN / 4);
    float4 v[8];
    #pragma unroll
    for (int i = 0; i < 8; ++i) v[i] = row[lane + (i << 6)];  // all 8 in flight

    const float* xr = x + (size_t)(lane & (HG_BC - 1)) * HG_N_IN;
    float mx = -INFINITY;
    int cnt = 0;

    #pragma unroll
    for (int i = 0; i < 8; ++i) {
        int code = (v[i].x != 0.0f) | ((v[i].y != 0.0f) << 1) |
                   ((v[i].z != 0.0f) << 2) | ((v[i].w != 0.0f) << 3);
        unsigned long long b = __ballot(code != 0);
        if (b == 0ull) continue;                  // wave-uniform skip
        while (b) {
            int s = __ffsll((unsigned long long)b) - 1;
            b &= b - 1;
            int c = __shfl(code, s);              // 4-bit component mask of lane s
            int nbase = (s + (i << 6)) << 2;      // column of lane s's float4
            while (c) {
                int j = __ffs(c) - 1;
                c &= c - 1;
                ++cnt;                            // wave-uniform total
                if (lane < HG_BC) mx = fmaxf(mx, xr[nbase + j]);
            }
        }
    }

    float res = (cnt == HG_N_IN) ? mx : fmaxf(mx, 0.0f);  // clamp iff a zero exists
    if (lane < HG_BC) r[w][lane] = res;
    __syncthreads();

    // transposed store: t -> (bc = t/16, dm = t%16); 16 consecutive floats per bc
    const int t = threadIdx.x;
    if (t < HG_BC * HG_RPB) {
        const int bc = t >> 4;
        const int dm = t & (HG_RPB - 1);
        out[(size_t)bc * HG_N_OUT + m0 + dm] = r[dm][bc];
    }
}

extern "C" void kernel_launch(void* const* d_in, const int* in_sizes, int n_in,
                              void* d_out, int out_size, void* d_ws, size_t ws_size,
                              hipStream_t stream) {
    const float* x    = (const float*)d_in[0];   // [2,16,2048] f32
    const float4* Bt4 = (const float4*)d_in[1];  // [4096,2048] f32 as float4
    float* out = (float*)d_out;                  // [2,16,4096] f32

    // 16 waves per block, one row per wave -> 256 blocks (1 per CU, 16 waves/CU)
    hg_rowmax<<<HG_N_OUT / HG_RPB, 1024, 0, stream>>>(Bt4, x, out);
}

// Round 7
// 11.589 us; speedup vs baseline: 1.1239x; 1.0630x over previous
//
#include <hip/hip_runtime.h>

// out[b,c,m] = max_n x[b,c,n] * Bt[m,n],  Bt binary {0,1}, ~3 ones per row of 2048.
// Exact sparse evaluation, one wave per row, 8 rows per 512-thread block:
//   - wave loads its 8 KB row as 8 nontemporal float4 per lane (coalesced,
//     doesn't evict the L2-resident x)
//   - one combined ballot per 256-element chunk skips empty chunks (~69%)
//   - non-empty chunks: 4 per-component ballots; gather addresses derive
//     purely from the wave-uniform masks (no data shuffles) -> all x gathers
//     issue back-to-back, the fmax chain waits on latency only once
//   - wave-uniform nonzero count: cnt < 2048 -> a zero term exists -> clamp
//     at 0 (the dense x*0 terms); cnt == 2048 -> no clamp (all-ones row)
//   - results staged in LDS, stored transposed (full 64 B lines, exact 512 KB)
// Every output element has exactly one writer -> plain stores, 1 dispatch.

#define HG_N_IN   2048
#define HG_N_OUT  4096
#define HG_BC     32      // BATCH * FEAT = 2*16
#define HG_RPB    8       // rows per block (= waves per block)

typedef float nf4 __attribute__((ext_vector_type(4)));  // native vec for nt-load

__global__ __launch_bounds__(512) void hg_rowmax(const nf4* __restrict__ Bt4,
                                                 const float* __restrict__ x,
                                                 float* __restrict__ out) {
    __shared__ float r[HG_RPB][HG_BC + 1];
    const int w    = threadIdx.x >> 6;           // wave id = row within block
    const int lane = threadIdx.x & 63;
    const int m0   = blockIdx.x * HG_RPB;
    const int m    = m0 + w;

    const nf4* row = Bt4 + (size_t)m * (HG_N_IN / 4);
    nf4 v[8];
    #pragma unroll
    for (int i = 0; i < 8; ++i)
        v[i] = __builtin_nontemporal_load(&row[lane + (i << 6)]);

    const float* xr = x + (size_t)(lane & (HG_BC - 1)) * HG_N_IN;
    float mx = -INFINITY;
    int cnt = 0;

    #pragma unroll
    for (int i = 0; i < 8; ++i) {
        const int f0 = (v[i].x != 0.0f), f1 = (v[i].y != 0.0f);
        const int f2 = (v[i].z != 0.0f), f3 = (v[i].w != 0.0f);
        unsigned long long any = __ballot((f0 | f1 | f2 | f3) != 0);
        if (any == 0ull) continue;               // wave-uniform skip (~69%)
        unsigned long long bm[4];
        bm[0] = __ballot(f0); bm[1] = __ballot(f1);
        bm[2] = __ballot(f2); bm[3] = __ballot(f3);
        #pragma unroll
        for (int j = 0; j < 4; ++j) {
            unsigned long long b = bm[j];
            while (b) {
                int s = __ffsll(b) - 1;
                b &= b - 1;
                ++cnt;                           // wave-uniform total
                int n = (((i << 6) + s) << 2) + j;
                if (lane < HG_BC) mx = fmaxf(mx, xr[n]);  // no cross-lane dep
            }
        }
    }

    float res = (cnt == HG_N_IN) ? mx : fmaxf(mx, 0.0f);  // clamp iff a zero exists
    if (lane < HG_BC) r[w][lane] = res;
    __syncthreads();

    // transposed store: 256 threads cover 8 rows x 32 channels, 32 B runs per bc
    const int t = threadIdx.x;
    if (t < HG_BC * HG_RPB) {
        const int bc = t >> 3;                   // 0..31
        const int dm = t & (HG_RPB - 1);         // 0..7
        out[(size_t)bc * HG_N_OUT + m0 + dm] = r[dm][bc];
    }
}

extern "C" void kernel_launch(void* const* d_in, const int* in_sizes, int n_in,
                              void* d_out, int out_size, void* d_ws, size_t ws_size,
                              hipStream_t stream) {
    const float* x  = (const float*)d_in[0];     // [2,16,2048] f32
    const nf4* Bt4  = (const nf4*)d_in[1];       // [4096,2048] f32 as float4
    float* out = (float*)d_out;                  // [2,16,4096] f32

    // 8 waves per block, one row per wave -> 512 blocks (2 blocks/CU)
    hg_rowmax<<<HG_N_OUT / HG_RPB, 512, 0, stream>>>(Bt4, x, out);
}

// Round 8
// 11.121 us; speedup vs baseline: 1.1712x; 1.0421x over previous
//
#include <hip/hip_runtime.h>

// out[b,c,m] = max_n x[b,c,n] * Bt[m,n],  Bt binary {0,1}, ~3 ones per row of 2048.
// Exact sparse evaluation, one wave per row, 8 rows per 512-thread block:
//   - wave loads its 8 KB row as 8 float4 per lane (coalesced, all in flight;
//     plain loads so the 256 MB L3 retains Bt across graph replays)
//   - one combined ballot per 256-element chunk skips empty chunks (~69%)
//   - non-empty chunks: 4 per-component ballots; gather addresses derive
//     purely from the wave-uniform masks (no data shuffles) -> all x gathers
//     issue back-to-back, the fmax chain waits on latency only once
//   - wave-uniform nonzero count: cnt < 2048 -> a zero term exists -> clamp
//     at 0 (the dense x*0 terms); cnt == 2048 -> no clamp (all-ones row)
//   - results staged in LDS, stored transposed (full 64 B lines, exact 512 KB)
// Every output element has exactly one writer -> plain stores, 1 dispatch.

#define HG_N_IN   2048
#define HG_N_OUT  4096
#define HG_BC     32      // BATCH * FEAT = 2*16
#define HG_RPB    8       // rows per block (= waves per block)

typedef float nf4 __attribute__((ext_vector_type(4)));

__global__ __launch_bounds__(512) void hg_rowmax(const nf4* __restrict__ Bt4,
                                                 const float* __restrict__ x,
                                                 float* __restrict__ out) {
    __shared__ float r[HG_RPB][HG_BC + 1];
    const int w    = threadIdx.x >> 6;           // wave id = row within block
    const int lane = threadIdx.x & 63;
    const int m0   = blockIdx.x * HG_RPB;
    const int m    = m0 + w;

    const nf4* row = Bt4 + (size_t)m * (HG_N_IN / 4);
    nf4 v[8];
    #pragma unroll
    for (int i = 0; i < 8; ++i)
        v[i] = row[lane + (i << 6)];             // plain loads: L3 retains Bt

    const float* xr = x + (size_t)(lane & (HG_BC - 1)) * HG_N_IN;
    float mx = -INFINITY;
    int cnt = 0;

    #pragma unroll
    for (int i = 0; i < 8; ++i) {
        const int f0 = (v[i].x != 0.0f), f1 = (v[i].y != 0.0f);
        const int f2 = (v[i].z != 0.0f), f3 = (v[i].w != 0.0f);
        unsigned long long any = __ballot((f0 | f1 | f2 | f3) != 0);
        if (any == 0ull) continue;               // wave-uniform skip (~69%)
        unsigned long long bm[4];
        bm[0] = __ballot(f0); bm[1] = __ballot(f1);
        bm[2] = __ballot(f2); bm[3] = __ballot(f3);
        #pragma unroll
        for (int j = 0; j < 4; ++j) {
            unsigned long long b = bm[j];
            while (b) {
                int s = __ffsll(b) - 1;
                b &= b - 1;
                ++cnt;                           // wave-uniform total
                int n = (((i << 6) + s) << 2) + j;
                if (lane < HG_BC) mx = fmaxf(mx, xr[n]);  // no cross-lane dep
            }
        }
    }

    float res = (cnt == HG_N_IN) ? mx : fmaxf(mx, 0.0f);  // clamp iff a zero exists
    if (lane < HG_BC) r[w][lane] = res;
    __syncthreads();

    // transposed store: 256 threads cover 8 rows x 32 channels, 32 B runs per bc
    const int t = threadIdx.x;
    if (t < HG_BC * HG_RPB) {
        const int bc = t >> 3;                   // 0..31
        const int dm = t & (HG_RPB - 1);         // 0..7
        out[(size_t)bc * HG_N_OUT + m0 + dm] = r[dm][bc];
    }
}

extern "C" void kernel_launch(void* const* d_in, const int* in_sizes, int n_in,
                              void* d_out, int out_size, void* d_ws, size_t ws_size,
                              hipStream_t stream) {
    const float* x  = (const float*)d_in[0];     // [2,16,2048] f32
    const nf4* Bt4  = (const nf4*)d_in[1];       // [4096,2048] f32 as float4
    float* out = (float*)d_out;                  // [2,16,4096] f32

    // 8 waves per block, one row per wave -> 512 blocks (2 blocks/CU)
    hg_rowmax<<<HG_N_OUT / HG_RPB, 512, 0, stream>>>(Bt4, x, out);
}